// Round 2
// baseline (281.755 us; speedup 1.0000x reference)
//
#include <hip/hip_runtime.h>

// pred/target: (B=2, C=1, H=192, W=192, D=192) fp32, D contiguous.
// 5x5x5 box mean (zero pad), ncc = cross^2/(vi*vj+1e-5), loss = -mean(ncc).
//
// R8 = R7 redesign (LDS-free separable window sums) + divergence fix.
//   d-sum: in registers (each lane owns a 6-float d-window -> d-pair)
//   w-sum: DPP row_shl lane tree (8 w-rows live in 8 adjacent lanes)
//   h-sum: per-lane circular ring; SLICES % 5 == 0 + unroll-5 -> static
//          ring index, zero shift movs
// R7 BUG (absmax = loss/2): the redistribution DPP was written inside a
// divergent ternary -> executed with exec = hi lanes only -> its lo-lane
// sources were inactive -> bound_ctrl returned 0 -> every odd-d output got
// An=0, ncc=0. Fix: DPP runs unconditionally (full exec), then v_cndmask.

#define HH 192
#define WW 192
#define DD 192
#define BB 2
#define WWDD (WW * DD)
#define HCHUNK 41
#define NSLAB 5               // 5*41 = 205 >= 192; disjoint output slabs
#define SLICES (HCHUNK + 4)   // 45 = 9*5 -> unroll-5 folds ring rotation
#define GX 12
#define GY 12
#define GZ (BB * NSLAB)
#define NBLK (GX * GY * GZ)   // 1440, % 8 == 0 -> bijective XCD swizzle

// row_shl:n (ctrl 0x100+n): lane i reads lane i+n within its 16-lane row
// row_shr:n (ctrl 0x110+n): lane i reads lane i-n
// bound_ctrl=true: out-of-row source -> 0 (only feeds unused lanes here)
// MUST be called under full exec: a source lane with EXEC=0 also reads 0.
template <int CTRL>
__device__ __forceinline__ float dpp_f(float x) {
    union { float f; int i; } a, r;
    a.f = x;
    r.i = __builtin_amdgcn_update_dpp(0, a.i, CTRL, 0xF, 0xF, true);
    return r.f;
}

__global__ __launch_bounds__(256, 6)
void lncc_fused_kernel(const float* __restrict__ pred,
                       const float* __restrict__ targ,
                       double* __restrict__ acc_out) {
    __shared__ float wpart[4];

    // XCD-aware swizzle: dispatch-consecutive blocks round-robin XCDs, so
    // give each XCD one contiguous 180-block chunk of tile space (w/d halo
    // neighbors then share one XCD's L2).
    int flat = blockIdx.x + GX * (blockIdx.y + GY * blockIdx.z);
    flat = (flat & 7) * (NBLK / 8) + (flat >> 3);
    const int bx  = flat % GX;
    const int byz = flat / GX;
    const int by  = byz % GY;
    const int bz  = byz / GY;

    const int tid  = threadIdx.x;
    const int wid  = tid >> 6;
    const int lane = tid & 63;
    const int rj = lane & 7;   // w-row within wave (lane-fast: DPP dist 1,2,4)
    const int dx = lane >> 3;  // d-pair within wave

    const int d0 = bx * 16;
    const int w0 = by * 16;
    const int b  = bz / NSLAB;
    const int h0 = (bz - b * NSLAB) * HCHUNK;
    const int base = b * (HH * WWDD);

    // wave tile: 4 w-outputs x 16 d-outputs; rows sw = ty_base-2 .. ty_base+5
    const int ty_base = w0 + 4 * wid;
    const int sw  = ty_base - 2 + rj;
    const int sdb = d0 + 2 * dx - 2;            // 6-float window start
    const bool row_ok = ((unsigned)sw < (unsigned)WW);
    const bool ok0 = row_ok && (sdb >= 0);      // floats sdb, sdb+1
    const bool ok1 = row_ok;                    // sdb+2..3 always in-range
    const bool ok2 = row_ok && (sdb + 5 < DD);  // floats sdb+4, sdb+5
    const int  gofs = base + sw * DD + sdb;     // deref only when masked ok
    const bool hi = (rj >= 4);

    float2 P0, P1, P2, T0, T1, T2;
    auto load_slice = [&](int h) {
        P0 = P1 = P2 = T0 = T1 = T2 = make_float2(0.f, 0.f);
        if ((unsigned)h < (unsigned)HH) {       // wave-uniform zero-pad guard
            const float* pp = pred + (gofs + h * WWDD);
            const float* tt = targ + (gofs + h * WWDD);
            if (ok0) { P0 = *(const float2*)pp;       T0 = *(const float2*)tt; }
            if (ok1) { P1 = *(const float2*)(pp + 2); T1 = *(const float2*)(tt + 2); }
            if (ok2) { P2 = *(const float2*)(pp + 4); T2 = *(const float2*)(tt + 4); }
        }
    };

    float ring[5][5];
#pragma unroll
    for (int q = 0; q < 5; ++q)
#pragma unroll
        for (int i = 0; i < 5; ++i) ring[q][i] = 0.f;
    float hs[5] = {0.f, 0.f, 0.f, 0.f, 0.f};
    float acc = 0.f;

#pragma unroll 1
    for (int mm = 0; mm < SLICES / 5; ++mm) {
#pragma unroll
        for (int u = 0; u < 5; ++u) {
            const int it = 5 * mm + u;
            load_slice(h0 - 2 + it);

            // ---- d-sums for the lane's d-pair (ea = even d, eb = odd d) ----
            const float p0=P0.x, p1=P0.y, p2=P1.x, p3=P1.y, p4=P2.x, p5=P2.y;
            const float q0=T0.x, q1=T0.y, q2=T1.x, q3=T1.y, q4=T2.x, q5=T2.y;
            float ea[5], eb[5];
            ea[0] = p0+p1+p2+p3+p4;  eb[0] = ea[0]-p0+p5;
            ea[1] = q0+q1+q2+q3+q4;  eb[1] = ea[1]-q0+q5;
            const float pp0=p0*p0, pp5=p5*p5;
            const float qq0=q0*q0, qq5=q5*q5;
            const float pq0=p0*q0, pq5=p5*q5;
            ea[2] = pp0+p1*p1+p2*p2+p3*p3+p4*p4;  eb[2] = ea[2]-pp0+pp5;
            ea[3] = qq0+q1*q1+q2*q2+q3*q3+q4*q4;  eb[3] = ea[3]-qq0+qq5;
            ea[4] = pq0+p1*q1+p2*q2+p3*q3+p4*q4;  eb[4] = ea[4]-pq0+pq5;

            // ---- w-sum: rows rj..rj+4 via DPP tree; valid at rj<4.
            // Redistribute: hi lanes take the odd-d window of lane-4, so all
            // 64 lanes own exactly one output column (4 ty x 16 d per wave).
            // ALL dpp_f calls straight-line / full-exec (see dpp_f comment).
            float An[5];
#pragma unroll
            for (int q = 0; q < 5; ++q) {
                const float va = ea[q], vb = eb[q];
                float sa = va + dpp_f<0x101>(va);        // rows rj,rj+1
                sa = sa + dpp_f<0x102>(sa);              // rows rj..rj+3
                const float Wa = sa + dpp_f<0x104>(va);  // + row rj+4
                float sb = vb + dpp_f<0x101>(vb);
                sb = sb + dpp_f<0x102>(sb);
                const float Wb = sb + dpp_f<0x104>(vb);
                const float Wbs = dpp_f<0x114>(Wb);      // row_shr:4, full exec
                An[q] = hi ? Wbs : Wa;                   // v_cndmask select
            }

            // ---- h ring: static slot u (it mod 5) holds An from it-5 ----
#pragma unroll
            for (int q = 0; q < 5; ++q) {
                hs[q] += An[q] - ring[q][u];
                ring[q][u] = An[q];
            }

            if (it >= 4) {                       // wave-uniform
                const int hout = h0 + it - 4;
                if (hout < HH) {
                    const float inv = 1.0f / 125.0f;
                    const float uI = hs[0]*inv, uJ = hs[1]*inv;
                    const float I2 = hs[2]*inv, J2 = hs[3]*inv, IJ = hs[4]*inv;
                    const float cross = IJ - uI * uJ;
                    const float vi = I2 - uI * uI;
                    const float vj = J2 - uJ * uJ;
                    acc += (cross * cross) *
                           __builtin_amdgcn_rcpf(vi * vj + 1e-5f);
                }
            }
        }
    }

    // ---- block reduction, one double atomic per block ----
#pragma unroll
    for (int off = 32; off > 0; off >>= 1) acc += __shfl_down(acc, off, 64);
    if (lane == 0) wpart[wid] = acc;
    __syncthreads();
    if (tid == 0)
        atomicAdd(acc_out, (double)(wpart[0] + wpart[1] + wpart[2] + wpart[3]));
}

__global__ void lncc_finalize_kernel(const double* __restrict__ acc,
                                     float* __restrict__ out) {
    const double n = (double)BB * HH * WW * DD;
    out[0] = (float)(-acc[0] / n);
}

extern "C" void kernel_launch(void* const* d_in, const int* in_sizes, int n_in,
                              void* d_out, int out_size, void* d_ws, size_t ws_size,
                              hipStream_t stream) {
    const float* pred = (const float*)d_in[0];
    const float* targ = (const float*)d_in[1];
    float* out = (float*)d_out;
    double* acc = (double*)d_ws;

    hipMemsetAsync(d_ws, 0, sizeof(double), stream);

    dim3 grid(GX, GY, GZ);     // 12 x 12 x 10 = 1440 blocks
    dim3 block(256, 1, 1);
    lncc_fused_kernel<<<grid, block, 0, stream>>>(pred, targ, acc);
    lncc_finalize_kernel<<<1, 1, 0, stream>>>(acc, out);
}